// Round 13
// baseline (357.831 us; speedup 1.0000x reference)
//
#include <hip/hip_runtime.h>
#include <cstdint>

#define KT   2048             // C*D
#define GR   4                // batches per tile (32 KB tile)
#define NBLK 256              // 1 block per CU
#define BPB  (65536 / NBLK)   // 256 batches per block
#define NT   (BPB / GR)       // 64 tiles per block
#define PST  36               // Pp row stride floats (32 payload + 4 pad, 16B-aligned)

typedef const __attribute__((address_space(1))) uint32_t gu32;
typedef __attribute__((address_space(3))) uint32_t lu32;

// W6 k-major: W6[k*2048 + j*256 + l*4 + dd] = W[jp][k][m], e = jp*32+m = (j*64+l)*4+dd
__global__ __launch_bounds__(1024) void wtrans_kernel(const float* __restrict__ W,
                                                      float* __restrict__ W6) {
    int jp = blockIdx.x;          // [0,64)
    int t = threadIdx.x;          // k*32 + m
    int k = t >> 5, m = t & 31;
    int e = jp * 32 + m;
    int e4 = e >> 2, dd = e & 3;
    int j = e4 >> 6, l = e4 & 63;
    W6[k * 2048 + j * 256 + l * 4 + dd] = W[jp * 1024 + t];
}

template <int CTRL>
__device__ __forceinline__ float dpp_add(float v) {
    int moved = __builtin_amdgcn_update_dpp(0, __float_as_int(v), CTRL, 0xF, 0xF, true);
    return v + __int_as_float(moved);
}

// 1024 threads = 16 waves = (jq: 4 j-quarters) x (ko: 4 k-octets); w = jq*4+ko.
// W slice = Wr[8k][2j] quads = 64 VGPR, loaded once. Thread covers 8 k per x-read:
// phase-1 ds_reads halved vs k-quad mapping. x in 4 LDS buffers, staged 3 ahead,
// counted vmcnt (never 0 mid-loop), 2 barriers per tile (R12-verified skeleton).
__global__ __launch_bounds__(1024, 1) void ipf_kernel(const float* __restrict__ x,
                                                      const float* __restrict__ W6,
                                                      float* __restrict__ out) {
    extern __shared__ float smem[];
    float* xs = smem;                  // 4 * 8192 floats (4 x 32 KB)
    float* Pp = smem + 4 * 8192;       // 64 rows x PST (wave w x 16-lane-group g2)
    float* Sl = Pp + 64 * PST;         // 128 floats: Sl[bb*32+k]
    const int t = threadIdx.x;
    const int w = t >> 6, l = t & 63;
    const int ko = w & 3;              // k-octet [8ko, 8ko+8)
    const int jq = w >> 2;             // j-quarter: j in {jq*2, jq*2+1}
    const long long bbase = (long long)blockIdx.x * BPB;
    const char* gx = (const char*)(x + bbase * KT);

    // ---- W slice -> 64 VGPRs, then drain so the VMEM counter is clean ----
    float4 Wr[8][2];
    #pragma unroll
    for (int q = 0; q < 8; ++q)
        #pragma unroll
        for (int jj = 0; jj < 2; ++jj)
            Wr[q][jj] = *(const float4*)(W6 + (ko * 8 + q) * 2048 + (jq * 2 + jj) * 256 + l * 4);
    __builtin_amdgcn_sched_barrier(0);
    asm volatile("s_waitcnt vmcnt(0)" ::: "memory");
    __builtin_amdgcn_sched_barrier(0);

    // stage tile tt (32 KB): wave stages 2 KB = 2 x 1KB DMA loads
    #define STAGE(tt, bf)                                                                   \
        {                                                                                   \
            const char* gs = gx + (size_t)(tt) * 32768 + w * 2048;                          \
            char* ld = (char*)(xs + (bf) * 8192) + w * 2048;                                \
            __builtin_amdgcn_global_load_lds((gu32*)(gs + l * 16), (lu32*)ld, 16, 0, 0);    \
            __builtin_amdgcn_global_load_lds((gu32*)(gs + 1024 + l * 16),                   \
                                             (lu32*)(ld + 1024), 16, 0, 0);                 \
        }

    STAGE(0, 0);
    STAGE(1, 1);
    STAGE(2, 2);

    #pragma unroll 1
    for (int tt = 0; tt < NT; ++tt) {
        // (A) counted wait for stage(tt); later stages + stores stay in flight.
        //     (identical queue walk to R12: stage=2 instr, store=1 instr per wave)
        if (tt >= 3 && tt < NT - 2)  asm volatile("s_waitcnt vmcnt(6)" ::: "memory");
        else if (tt == 2)            asm volatile("s_waitcnt vmcnt(5)" ::: "memory");
        else if (tt <= 1)            asm volatile("s_waitcnt vmcnt(4)" ::: "memory");
        else if (tt == NT - 2)       asm volatile("s_waitcnt vmcnt(4)" ::: "memory");
        else                         asm volatile("s_waitcnt vmcnt(2)" ::: "memory");
        __builtin_amdgcn_s_barrier();   // buf(tt) resident; Sl(tt-1) visible; Pp reusable
        __builtin_amdgcn_sched_barrier(0);

        // (B) compute tile tt: 2 jj x {4 ds_read_b128, 128 FMA}
        const float* xc = xs + (tt & 3) * 8192;
        float acc[GR][8];
        #pragma unroll
        for (int bb = 0; bb < GR; ++bb)
            #pragma unroll
            for (int q = 0; q < 8; ++q) acc[bb][q] = 0.0f;
        #pragma unroll
        for (int jj = 0; jj < 2; ++jj) {
            float4 xv[GR];
            #pragma unroll
            for (int bb = 0; bb < GR; ++bb)
                xv[bb] = *(const float4*)(xc + bb * 2048 + (jq * 2 + jj) * 256 + l * 4);
            #pragma unroll
            for (int bb = 0; bb < GR; ++bb)
                #pragma unroll
                for (int q = 0; q < 8; ++q) {
                    acc[bb][q] += xv[bb].x * Wr[q][jj].x;
                    acc[bb][q] += xv[bb].y * Wr[q][jj].y;
                    acc[bb][q] += xv[bb].z * Wr[q][jj].z;
                    acc[bb][q] += xv[bb].w * Wr[q][jj].w;
                }
        }
        // 16-lane DPP reduce -> lane (l&15)==15 holds 16-lane sum
        #pragma unroll
        for (int bb = 0; bb < GR; ++bb)
            #pragma unroll
            for (int q = 0; q < 8; ++q) {
                float v = acc[bb][q];
                v = dpp_add<0x111>(v);
                v = dpp_add<0x112>(v);
                v = dpp_add<0x114>(v);
                v = dpp_add<0x118>(v);      // row_shr:8 within 16-lane DPP row
                acc[bb][q] = v;
            }
        if ((l & 15) == 15) {
            float* row = Pp + (w * 4 + (l >> 4)) * PST;
            #pragma unroll
            for (int bb = 0; bb < GR; ++bb) {
                *(float4*)(row + bb * 8)     = make_float4(acc[bb][0], acc[bb][1], acc[bb][2], acc[bb][3]);
                *(float4*)(row + bb * 8 + 4) = make_float4(acc[bb][4], acc[bb][5], acc[bb][6], acc[bb][7]);
            }
        }

        // (C) phase 2 of tile tt-1, same interval (independent of B)
        if (tt > 0) {
            const int tp = tt - 1;
            const float* xg = xs + (tp & 3) * 8192;
            const int o = t >> 2, h = t & 3;       // o in [0,256) = 4bb x 64i
            const int bb = o >> 6, i = o & 63;
            const int qa = (i + h) & 7, qb = qa ^ 4;
            const float4 xa = *(const float4*)(xg + bb * 2048 + i * 32 + qa * 4);
            const float4 sa = *(const float4*)(Sl + bb * 32 + qa * 4);
            const float4 xv2 = *(const float4*)(xg + bb * 2048 + i * 32 + qb * 4);
            const float4 sb = *(const float4*)(Sl + bb * 32 + qb * 4);
            float s = xa.x * sa.x + xa.y * sa.y + xa.z * sa.z + xa.w * sa.w
                    + xv2.x * sb.x + xv2.y * sb.y + xv2.z * sb.z + xv2.w * sb.w;
            s = dpp_add<0x111>(s);
            s = dpp_add<0x112>(s);                 // lane h==3 holds 8-quad dot
            if (h == 3) {
                const float e2 = __expf(2.0f * s); // tanh = 1 - 2/(e^{2s}+1)
                out[(bbase + (long long)tp * GR + bb) * 64 + i] = 1.0f - 2.0f / (e2 + 1.0f);
            }
        }

        asm volatile("s_waitcnt lgkmcnt(0)" ::: "memory");
        __builtin_amdgcn_s_barrier();              // Pp(tt) visible; C-reads of reused buf done
        __builtin_amdgcn_sched_barrier(0);

        // (D) gather: Sl[sv] = sum of 16 partials (4 jq x 4 g2); 8-lane groups
        {
            const int sv = w * 8 + (l >> 3);       // [0,128)
            const int r = l & 7;
            const int bb = sv >> 5, k = sv & 31;
            const int kk = k & 7, kO = k >> 3;
            const int p0 = r, p1 = r + 8;          // partial p = jq*4 + g2
            const int row0 = ((p0 >> 2) * 4 + kO) * 4 + (p0 & 3);
            const int row1 = ((p1 >> 2) * 4 + kO) * 4 + (p1 & 3);
            float v = Pp[row0 * PST + bb * 8 + kk] + Pp[row1 * PST + bb * 8 + kk];
            v = dpp_add<0x111>(v);
            v = dpp_add<0x112>(v);
            v = dpp_add<0x114>(v);                 // lane r==7 holds the 16-partial sum
            if (r == 7) Sl[sv] = v;
        }
        asm volatile("s_waitcnt lgkmcnt(0)" ::: "memory");

        // (E) stage tile tt+3 into buf[(tt+3)&3] — C(tt-1)'s reads of that buffer
        //     drained before the barrier above; issued as newest VMEM ops.
        if (tt + 3 < NT) STAGE(tt + 3, (tt + 3) & 3);
        __builtin_amdgcn_sched_barrier(0);
        // loop-top barrier orders Sl writes before next interval's phase-2 reads
    }

    // epilogue: phase 2 of the last tile
    __builtin_amdgcn_s_barrier();
    {
        const int tp = NT - 1;
        const float* xg = xs + (tp & 3) * 8192;
        const int o = t >> 2, h = t & 3;
        const int bb = o >> 6, i = o & 63;
        const int qa = (i + h) & 7, qb = qa ^ 4;
        const float4 xa = *(const float4*)(xg + bb * 2048 + i * 32 + qa * 4);
        const float4 sa = *(const float4*)(Sl + bb * 32 + qa * 4);
        const float4 xv2 = *(const float4*)(xg + bb * 2048 + i * 32 + qb * 4);
        const float4 sb = *(const float4*)(Sl + bb * 32 + qb * 4);
        float s = xa.x * sa.x + xa.y * sa.y + xa.z * sa.z + xa.w * sa.w
                + xv2.x * sb.x + xv2.y * sb.y + xv2.z * sb.z + xv2.w * sb.w;
        s = dpp_add<0x111>(s);
        s = dpp_add<0x112>(s);
        if (h == 3) {
            const float e2 = __expf(2.0f * s);
            out[(bbase + (long long)tp * GR + bb) * 64 + i] = 1.0f - 2.0f / (e2 + 1.0f);
        }
    }
    #undef STAGE
}

extern "C" void kernel_launch(void* const* d_in, const int* in_sizes, int n_in,
                              void* d_out, int out_size, void* d_ws, size_t ws_size,
                              hipStream_t stream) {
    const float* x = (const float*)d_in[0];   // [65536,64,32] fp32
    const float* W = (const float*)d_in[1];   // [64,32,32] fp32
    float* out = (float*)d_out;               // [65536,64] fp32
    float* W6  = (float*)d_ws;                // 65536 floats = 256 KB scratch

    const size_t smem_bytes = (size_t)(4 * 8192 + 64 * PST + 128) * sizeof(float); // 140800
    hipFuncSetAttribute((const void*)ipf_kernel,
                        hipFuncAttributeMaxDynamicSharedMemorySize, (int)smem_bytes);

    wtrans_kernel<<<64, 1024, 0, stream>>>(W, W6);
    ipf_kernel<<<NBLK, 1024, smem_bytes, stream>>>(x, W6, out);
}

// Round 14
// 308.455 us; speedup vs baseline: 1.1601x; 1.1601x over previous
//
#include <hip/hip_runtime.h>
#include <cstdint>

#define KT   2048             // C*D
#define GR   2                // batches per tile (16 KB tile)
#define NBLK 256              // 1 block per CU
#define BPB  (65536 / NBLK)   // 256 batches per block
#define NT   (BPB / GR)       // 128 tiles per block
#define PST  20               // Pp row stride floats (16 payload + 4 pad, 16B-aligned)

typedef const __attribute__((address_space(1))) uint32_t gu32;
typedef __attribute__((address_space(3))) uint32_t lu32;

// W6 k-major: W6[k*2048 + j*256 + l*4 + dd] = W[jp][k][m], e = jp*32+m = (j*64+l)*4+dd
__global__ __launch_bounds__(1024) void wtrans_kernel(const float* __restrict__ W,
                                                      float* __restrict__ W6) {
    int jp = blockIdx.x;          // [0,64)
    int t = threadIdx.x;          // k*32 + m
    int k = t >> 5, m = t & 31;
    int e = jp * 32 + m;
    int e4 = e >> 2, dd = e & 3;
    int j = e4 >> 6, l = e4 & 63;
    W6[k * 2048 + j * 256 + l * 4 + dd] = W[jp * 1024 + t];
}

template <int CTRL>
__device__ __forceinline__ float dpp_add(float v) {
    int moved = __builtin_amdgcn_update_dpp(0, __float_as_int(v), CTRL, 0xF, 0xF, true);
    return v + __int_as_float(moved);
}

// 1024 threads = 16 waves = (jq: 4 j-quarters) x (ko: 4 k-octets); w = jq*4+ko.
// Wr[8k][2slice] quads = 64 VGPR; acc[2][8]=16; total ~105 VGPR (under the 128
// cap for 16 waves/CU — R13's AGPR-offload trigger was ~130). 16 KB tiles,
// 4 LDS buffers, staged 3 ahead, counted vmcnt (never 0 mid-loop), 2 barriers/tile.
__global__ __launch_bounds__(1024, 4) void ipf_kernel(const float* __restrict__ x,
                                                      const float* __restrict__ W6,
                                                      float* __restrict__ out) {
    extern __shared__ float smem[];
    float* xs = smem;                  // 4 * 4096 floats (4 x 16 KB)
    float* Pp = smem + 4 * 4096;       // 64 rows x PST
    float* Sl = Pp + 64 * PST;         // 64 floats: Sl[bb*32+k]
    const int t = threadIdx.x;
    const int w = t >> 6, l = t & 63;
    const int ko = w & 3;              // k-octet [8ko, 8ko+8)
    const int jq = w >> 2;             // slices {jq*2, jq*2+1} (8 slices of 256 e)
    const long long bbase = (long long)blockIdx.x * BPB;
    const char* gx = (const char*)(x + bbase * KT);

    // ---- W slice -> 64 VGPRs, then drain so the VMEM counter is clean ----
    float4 Wr[8][2];
    #pragma unroll
    for (int q = 0; q < 8; ++q)
        #pragma unroll
        for (int jj = 0; jj < 2; ++jj)
            Wr[q][jj] = *(const float4*)(W6 + (ko * 8 + q) * 2048 + (jq * 2 + jj) * 256 + l * 4);
    __builtin_amdgcn_sched_barrier(0);
    asm volatile("s_waitcnt vmcnt(0)" ::: "memory");
    __builtin_amdgcn_sched_barrier(0);

    // stage tile tt (16 KB): wave stages 1 KB = ONE DMA instr
    #define STAGE(tt, bf)                                                              \
        __builtin_amdgcn_global_load_lds(                                              \
            (gu32*)(gx + (size_t)(tt) * 16384 + w * 1024 + l * 16),                    \
            (lu32*)((char*)(xs + (bf) * 4096) + w * 1024), 16, 0, 0)

    STAGE(0, 0);
    STAGE(1, 1);
    STAGE(2, 2);

    #pragma unroll 1
    for (int tt = 0; tt < NT; ++tt) {
        // (A) counted wait for stage(tt). Per-wave VMEM instrs: stage=1, store=1.
        //     Queue walk: tt<=1:[s,s,s]->2; tt==2:[s,s,st,s]->3;
        //     3<=tt<=NT-3: [s(tt),st,s,st,s]->4; tt==NT-2:->3; tt==NT-1:->2.
        if (tt >= 3 && tt <= NT - 3)  asm volatile("s_waitcnt vmcnt(4)" ::: "memory");
        else if (tt == 2)             asm volatile("s_waitcnt vmcnt(3)" ::: "memory");
        else if (tt <= 1)             asm volatile("s_waitcnt vmcnt(2)" ::: "memory");
        else if (tt == NT - 2)        asm volatile("s_waitcnt vmcnt(3)" ::: "memory");
        else                          asm volatile("s_waitcnt vmcnt(2)" ::: "memory");
        __builtin_amdgcn_s_barrier();   // buf(tt) resident; Sl(tt-1) visible; Pp reusable
        __builtin_amdgcn_sched_barrier(0);

        // (B) compute tile tt: 2 jj x {2 ds_read_b128, 64 FMA}
        const float* xc = xs + (tt & 3) * 4096;
        float acc[GR][8];
        #pragma unroll
        for (int bb = 0; bb < GR; ++bb)
            #pragma unroll
            for (int q = 0; q < 8; ++q) acc[bb][q] = 0.0f;
        #pragma unroll
        for (int jj = 0; jj < 2; ++jj) {
            float4 xv[GR];
            #pragma unroll
            for (int bb = 0; bb < GR; ++bb)
                xv[bb] = *(const float4*)(xc + bb * 2048 + (jq * 2 + jj) * 256 + l * 4);
            #pragma unroll
            for (int bb = 0; bb < GR; ++bb)
                #pragma unroll
                for (int q = 0; q < 8; ++q) {
                    acc[bb][q] += xv[bb].x * Wr[q][jj].x;
                    acc[bb][q] += xv[bb].y * Wr[q][jj].y;
                    acc[bb][q] += xv[bb].z * Wr[q][jj].z;
                    acc[bb][q] += xv[bb].w * Wr[q][jj].w;
                }
        }
        // 16-lane DPP reduce -> lane (l&15)==15 holds 16-lane sum
        #pragma unroll
        for (int bb = 0; bb < GR; ++bb)
            #pragma unroll
            for (int q = 0; q < 8; ++q) {
                float v = acc[bb][q];
                v = dpp_add<0x111>(v);
                v = dpp_add<0x112>(v);
                v = dpp_add<0x114>(v);
                v = dpp_add<0x118>(v);
                acc[bb][q] = v;
            }
        if ((l & 15) == 15) {
            float* row = Pp + (w * 4 + (l >> 4)) * PST;
            #pragma unroll
            for (int bb = 0; bb < GR; ++bb) {
                *(float4*)(row + bb * 8)     = make_float4(acc[bb][0], acc[bb][1], acc[bb][2], acc[bb][3]);
                *(float4*)(row + bb * 8 + 4) = make_float4(acc[bb][4], acc[bb][5], acc[bb][6], acc[bb][7]);
            }
        }

        // (C) phase 2 of tile tt-1 (independent of B): 8-lane groups, rotated b32
        //     reads -> exactly 2 lanes/bank (free), no quad-alias 8-way conflicts.
        if (tt > 0) {
            const int tp = tt - 1;
            const float* xg = xs + (tp & 3) * 4096;
            const int o = t >> 3, h = t & 7;       // o in [0,128) = 2bb x 64i
            const int bb = o >> 6, i = o & 63;
            float s = 0.0f;
            #pragma unroll
            for (int u = 0; u < 4; ++u) {
                const int d = (h * 4 + u + i) & 31;
                s += xg[bb * 2048 + i * 32 + d] * Sl[bb * 32 + d];
            }
            s = dpp_add<0x111>(s);
            s = dpp_add<0x112>(s);
            s = dpp_add<0x114>(s);                 // lane h==7 holds the 32-d dot
            if (h == 7) {
                const float e2 = __expf(2.0f * s); // tanh = 1 - 2/(e^{2s}+1)
                out[(bbase + (long long)tp * GR + bb) * 64 + i] = 1.0f - 2.0f / (e2 + 1.0f);
            }
        }

        asm volatile("s_waitcnt lgkmcnt(0)" ::: "memory");
        __builtin_amdgcn_s_barrier();              // Pp(tt) visible; C-reads of reused buf done
        __builtin_amdgcn_sched_barrier(0);

        // (D) gather: Sl[sv] = sum of 16 partials (4 jq x 4 g2); 16-lane groups
        {
            const int sv = t >> 4;                 // [0,64) = 2bb x 32k
            const int r = t & 15;
            const int bb = sv >> 5, k = sv & 31;
            const int row = ((r >> 2) * 4 + (k >> 3)) * 4 + (r & 3);  // (jq*4+ko)*4+g2
            float v = Pp[row * PST + bb * 8 + (k & 7)];
            v = dpp_add<0x111>(v);
            v = dpp_add<0x112>(v);
            v = dpp_add<0x114>(v);
            v = dpp_add<0x118>(v);                 // lane r==15 holds the 16-partial sum
            if (r == 15) Sl[sv] = v;
        }
        asm volatile("s_waitcnt lgkmcnt(0)" ::: "memory");

        // (E) stage tile tt+3 into buf[(tt+3)&3] — C(tt-1)'s reads of that buffer
        //     completed before the mid barrier; issued as newest VMEM op.
        if (tt + 3 < NT) STAGE(tt + 3, (tt + 3) & 3);
        __builtin_amdgcn_sched_barrier(0);
        // loop-top barrier orders Sl writes before next interval's phase-2 reads
    }

    // epilogue: phase 2 of the last tile
    __builtin_amdgcn_s_barrier();
    {
        const int tp = NT - 1;
        const float* xg = xs + (tp & 3) * 4096;
        const int o = t >> 3, h = t & 7;
        const int bb = o >> 6, i = o & 63;
        float s = 0.0f;
        #pragma unroll
        for (int u = 0; u < 4; ++u) {
            const int d = (h * 4 + u + i) & 31;
            s += xg[bb * 2048 + i * 32 + d] * Sl[bb * 32 + d];
        }
        s = dpp_add<0x111>(s);
        s = dpp_add<0x112>(s);
        s = dpp_add<0x114>(s);
        if (h == 7) {
            const float e2 = __expf(2.0f * s);
            out[(bbase + (long long)tp * GR + bb) * 64 + i] = 1.0f - 2.0f / (e2 + 1.0f);
        }
    }
    #undef STAGE
}

extern "C" void kernel_launch(void* const* d_in, const int* in_sizes, int n_in,
                              void* d_out, int out_size, void* d_ws, size_t ws_size,
                              hipStream_t stream) {
    const float* x = (const float*)d_in[0];   // [65536,64,32] fp32
    const float* W = (const float*)d_in[1];   // [64,32,32] fp32
    float* out = (float*)d_out;               // [65536,64] fp32
    float* W6  = (float*)d_ws;                // 65536 floats = 256 KB scratch

    const size_t smem_bytes = (size_t)(4 * 4096 + 64 * PST + 64) * sizeof(float); // 70912 B
    hipFuncSetAttribute((const void*)ipf_kernel,
                        hipFuncAttributeMaxDynamicSharedMemorySize, (int)smem_bytes);

    wtrans_kernel<<<64, 1024, 0, stream>>>(W, W6);
    ipf_kernel<<<NBLK, 1024, smem_bytes, stream>>>(x, W6, out);
}

// Round 15
// 207.157 us; speedup vs baseline: 1.7273x; 1.4890x over previous
//
#include <hip/hip_runtime.h>
#include <cstdint>

typedef __attribute__((ext_vector_type(8))) short short8;
typedef __attribute__((ext_vector_type(4))) float f32x4;

__device__ __forceinline__ unsigned short bf16_rne(float f) {
    unsigned u = __float_as_uint(f);
    u += 0x7FFFu + ((u >> 16) & 1u);
    return (unsigned short)(u >> 16);
}

// W fragment table for mfma_f32_16x16x32_bf16 B-operand:
// B[k(32) x j(16)] per k-step: lane holds col j = l&15, rows k = (l>>4)*8 + b.
// tab ushort idx: (((ks*2+nh)*2 + h)*64 + lane)*8 + b   (h: 0=hi, 1=lo)
// Wt[e][k] = W[jp][k][m], e = jp*32+m.
__global__ __launch_bounds__(1024) void wtab_kernel(const float* __restrict__ W,
                                                    unsigned short* __restrict__ tab) {
    int el = blockIdx.x * 1024 + threadIdx.x;   // 65536 elements
    int b    = el & 7;
    int lane = (el >> 3) & 63;
    int nh   = (el >> 9) & 1;
    int ks   = el >> 10;
    int e = ks * 32 + (lane >> 4) * 8 + b;
    int k = nh * 16 + (lane & 15);
    int jp = e >> 5, m = e & 31;
    float w = W[jp * 1024 + k * 32 + m];
    unsigned short hi = bf16_rne(w);
    float fh = __uint_as_float((unsigned)hi << 16);
    unsigned short lo = bf16_rne(w - fh);
    tab[(((ks * 2 + nh) * 2 + 0) * 64 + lane) * 8 + b] = hi;
    tab[(((ks * 2 + nh) * 2 + 1) * 64 + lane) * 8 + b] = lo;
}

__device__ __forceinline__ void split8(const float4& a, const float4& b,
                                       short8& hi, short8& lo) {
    float f[8] = {a.x, a.y, a.z, a.w, b.x, b.y, b.z, b.w};
    #pragma unroll
    for (int u = 0; u < 8; ++u) {
        unsigned short h = bf16_rne(f[u]);
        hi[u] = (short)h;
        float fh = __uint_as_float((unsigned)h << 16);
        lo[u] = (short)bf16_rne(f[u] - fh);
    }
}

// 256 threads = 4 independent waves; wave owns M-tile of 16 batches. No barriers.
// k-loop: A = x fragments (global, 16 rows x 128B coalesced), B = W table (L2-hot),
// 3-pass split-bf16 MFMA; C accumulates in AGPRs. Phase 2: S via per-wave LDS,
// x re-read from L2/L3 (just streamed), coalesced stores.
__global__ __launch_bounds__(256) void ipf_kernel(const float* __restrict__ x,
                                                  const unsigned short* __restrict__ tab,
                                                  float* __restrict__ out) {
    __shared__ float Sl[4][16 * 36];
    const int t = threadIdx.x;
    const int w = t >> 6, l = t & 63;
    const long long b0 = ((long long)blockIdx.x * 4 + w) * 16;

    const float* xrow = x + (b0 + (l & 15)) * 2048 + (l >> 4) * 8;   // A-frag base
    f32x4 c0 = {0.f, 0.f, 0.f, 0.f};
    f32x4 c1 = {0.f, 0.f, 0.f, 0.f};

    #pragma unroll 2
    for (int ks = 0; ks < 64; ++ks) {
        const float4 xa = *(const float4*)(xrow + ks * 32);
        const float4 xb = *(const float4*)(xrow + ks * 32 + 4);
        const short8* tp = (const short8*)(tab + ks * 2048);   // 2048 ushorts per ks
        const short8 wh0 = tp[l];            // nh0 hi
        const short8 wl0 = tp[64 + l];       // nh0 lo
        const short8 wh1 = tp[128 + l];      // nh1 hi
        const short8 wl1 = tp[192 + l];      // nh1 lo
        short8 xhi, xlo;
        split8(xa, xb, xhi, xlo);
        c0 = __builtin_amdgcn_mfma_f32_16x16x32_bf16(xhi, wh0, c0, 0, 0, 0);
        c1 = __builtin_amdgcn_mfma_f32_16x16x32_bf16(xhi, wh1, c1, 0, 0, 0);
        c0 = __builtin_amdgcn_mfma_f32_16x16x32_bf16(xhi, wl0, c0, 0, 0, 0);
        c1 = __builtin_amdgcn_mfma_f32_16x16x32_bf16(xhi, wl1, c1, 0, 0, 0);
        c0 = __builtin_amdgcn_mfma_f32_16x16x32_bf16(xlo, wh0, c0, 0, 0, 0);
        c1 = __builtin_amdgcn_mfma_f32_16x16x32_bf16(xlo, wh1, c1, 0, 0, 0);
    }

    // D layout (m89-verified): row(batch) = (l>>4)*4 + r, col(k) = l&15.
    float* S = &Sl[w][0];                    // stride 36: write conflicts <=2-way
    #pragma unroll
    for (int r = 0; r < 4; ++r) {
        S[((l >> 4) * 4 + r) * 36 + (l & 15)]      = c0[r];
        S[((l >> 4) * 4 + r) * 36 + 16 + (l & 15)] = c1[r];
    }
    asm volatile("s_waitcnt lgkmcnt(0)" ::: "memory");   // wave-local LDS, no barrier

    // phase 2: out[b0+r, i=l] = tanh(sum_d x[b0+r][l*32+d] * S[r][d])
    const float* xb2 = x + b0 * 2048;
    #pragma unroll 1
    for (int r = 0; r < 16; ++r) {
        const float* xr = xb2 + r * 2048 + l * 32;     // 64 lanes x 128B contiguous
        const float* sr = S + r * 36;                  // broadcast reads
        float s = 0.0f;
        #pragma unroll
        for (int q = 0; q < 8; ++q) {
            const float4 xv = *(const float4*)(xr + q * 4);
            s += xv.x * sr[q * 4] + xv.y * sr[q * 4 + 1]
               + xv.z * sr[q * 4 + 2] + xv.w * sr[q * 4 + 3];
        }
        const float e2 = __expf(2.0f * s);             // tanh = 1 - 2/(e^{2s}+1)
        out[(b0 + r) * 64 + l] = 1.0f - 2.0f / (e2 + 1.0f);
    }
}

extern "C" void kernel_launch(void* const* d_in, const int* in_sizes, int n_in,
                              void* d_out, int out_size, void* d_ws, size_t ws_size,
                              hipStream_t stream) {
    const float* x = (const float*)d_in[0];          // [65536,64,32] fp32
    const float* W = (const float*)d_in[1];          // [64,32,32] fp32
    float* out = (float*)d_out;                      // [65536,64] fp32
    unsigned short* tab = (unsigned short*)d_ws;     // 131072 ushorts = 256 KB

    wtab_kernel<<<64, 1024, 0, stream>>>(W, tab);
    ipf_kernel<<<1024, 256, 0, stream>>>(x, tab, out);
}